// Round 1
// baseline (600.168 us; speedup 1.0000x reference)
//
#include <hip/hip_runtime.h>
#include <math.h>

#define N_NODES 3200
#define E_EDGES 50000
#define RBFN 16
#define HID 128
#define NS 32
#define NV 16
#define DD 80
#define WNUM 2304
#define CUTF 5.0f
#define EPSF 1e-8f

__device__ __forceinline__ float sigm(float x) { return 1.0f / (1.0f + __expf(-x)); }
__device__ __forceinline__ float silu_f(float x) { return x * sigm(x); }

// ---------------- K1: irrep norm  (one 64-thread block per node) ----------------
__global__ void k_norm(const float* __restrict__ x, const float* __restrict__ nw,
                       const float* __restrict__ nb, float* __restrict__ xn) {
    int n = blockIdx.x, t = threadIdx.x;
    __shared__ float row[DD];
    const float* xr = x + n * DD;
    row[t] = xr[t];
    if (t < DD - 64) row[64 + t] = xr[64 + t];
    __syncthreads();
    float mean = 0.f;
#pragma unroll
    for (int i = 0; i < NS; i++) mean += row[i];
    mean *= (1.0f / NS);
    float var = 0.f;
#pragma unroll
    for (int i = 0; i < NS; i++) { float d = row[i] - mean; var += d * d; }
    var *= (1.0f / NS);
    float inv = rsqrtf(var + EPSF);
    if (t < NS) {
        float v = (row[t] - mean) * inv;
        xn[n * DD + t] = v * nw[t] + nb[t];
    }
    if (t < 48) {
        int j = t / 3;
        float v0 = row[NS + 3 * j], v1 = row[NS + 3 * j + 1], v2 = row[NS + 3 * j + 2];
        float rms = sqrtf((v0 * v0 + v1 * v1 + v2 * v2) * (1.0f / 3.0f) + EPSF);
        float v = row[NS + t] / rms;
        xn[n * DD + NS + t] = v * nw[NS + t] + nb[NS + t];
    }
}

// ------------- K2a: edge MLP layer 1 + gate + cutoff + den atomic ---------------
// wave owns 16 edges; rbf via scalar loads; lanes are the 128 output channels (2 groups)
__global__ __launch_bounds__(256) void k_edge_mlp1(
    const float* __restrict__ rbf, const float* __restrict__ elen,
    const int* __restrict__ dst,
    const float* __restrict__ mw1, const float* __restrict__ mb1,
    const float* __restrict__ gw1, const float* __restrict__ gb1,
    const float* __restrict__ gw2, const float* __restrict__ gb2,
    float* __restrict__ h1g, float* __restrict__ ewg, float* __restrict__ den) {
    int wv = __builtin_amdgcn_readfirstlane(threadIdx.x >> 6) + blockIdx.x * 4;
    int lane = threadIdx.x & 63;
    int eb = wv * 16;
    if (eb >= E_EDGES) return;
    int c0 = lane, c1 = 64 + lane;
    float t0[16], t1[16], g0[16], g1[16];
    float b0 = mb1[c0], b1 = mb1[c1], gb0v = gb1[c0], gb1v = gb1[c1];
#pragma unroll
    for (int e = 0; e < 16; e++) { t0[e] = b0; t1[e] = b1; g0[e] = gb0v; g1[e] = gb1v; }
#pragma unroll
    for (int r = 0; r < RBFN; r++) {
        float w0 = mw1[r * HID + c0], w1 = mw1[r * HID + c1];
        float v0 = gw1[r * HID + c0], v1 = gw1[r * HID + c1];
#pragma unroll
        for (int e = 0; e < 16; e++) {
            float rv = rbf[(eb + e) * RBFN + r];  // wave-uniform -> s_load
            t0[e] += rv * w0; t1[e] += rv * w1;
            g0[e] += rv * v0; g1[e] += rv * v1;
        }
    }
    float q0 = gw2[c0], q1 = gw2[c1];
    float gb2v = gb2[0];
#pragma unroll
    for (int e = 0; e < 16; e++) {
        h1g[(eb + e) * HID + c0] = silu_f(t0[e]);
        h1g[(eb + e) * HID + c1] = silu_f(t1[e]);
        float p = silu_f(g0[e]) * q0 + silu_f(g1[e]) * q1;
        p += __shfl_xor(p, 1);  p += __shfl_xor(p, 2);  p += __shfl_xor(p, 4);
        p += __shfl_xor(p, 8);  p += __shfl_xor(p, 16); p += __shfl_xor(p, 32);
        if (lane == 0) {
            float len = elen[eb + e];
            float cut = (len <= CUTF) ? 0.5f * (cosf(3.14159265358979f * len / CUTF) + 1.0f) : 0.f;
            float ew = cut * sigm(p + gb2v);
            ewg[eb + e] = ew;
            atomicAdd(&den[dst[eb + e]], ew);
        }
    }
}

// ---------------------- K2b: edge MLP layer 2 (128x128) -------------------------
__global__ __launch_bounds__(256) void k_edge_mlp2(
    const float* __restrict__ h1g, const float* __restrict__ mw2,
    const float* __restrict__ mb2, float* __restrict__ h2g) {
    int wv = __builtin_amdgcn_readfirstlane(threadIdx.x >> 6) + blockIdx.x * 4;
    int lane = threadIdx.x & 63;
    int eb = wv * 16;
    if (eb >= E_EDGES) return;
    int c0 = lane, c1 = 64 + lane;
    float t0[16], t1[16];
    float b0 = mb2[c0], b1 = mb2[c1];
#pragma unroll
    for (int e = 0; e < 16; e++) { t0[e] = b0; t1[e] = b1; }
#pragma unroll 4
    for (int k = 0; k < HID; k++) {
        float w0 = mw2[k * HID + c0], w1 = mw2[k * HID + c1];
#pragma unroll
        for (int e = 0; e < 16; e++) {
            float h = h1g[(eb + e) * HID + k];  // wave-uniform -> s_load
            t0[e] += h * w0; t1[e] += h * w1;
        }
    }
#pragma unroll
    for (int e = 0; e < 16; e++) {
        h2g[(eb + e) * HID + c0] = silu_f(t0[e]);
        h2g[(eb + e) * HID + c1] = silu_f(t1[e]);
    }
}

// -------- K3: fused tpw GEMM + tensor-product messages + scatter-add ------------
// block = 256 thr = 4 waves; wave owns TE edges; 6 column passes of 6 J-groups.
// column c = 64*J + lane; J<16:w1, J<24:w2, J<32:w3, else w4 (region-aligned).
#define TE 10
#define EB 40

__global__ __launch_bounds__(256, 3) void k_msg(
    const float* __restrict__ xn, const float* __restrict__ h2g,
    const float* __restrict__ ewg, const int* __restrict__ esrc,
    const int* __restrict__ edst, const float* __restrict__ esh,
    const float* __restrict__ mw3, const float* __restrict__ mb3,
    float* __restrict__ agg) {
    __shared__ float xrow[EB * DD];
    __shared__ float shl[EB * 4];
    __shared__ float ewl[EB];
    __shared__ int dstl[EB];
    int tid = threadIdx.x;
    int e0 = blockIdx.x * EB;
    for (int idx = tid; idx < EB * DD; idx += 256) {
        int ee = idx / DD, q = idx - ee * DD;
        int e = e0 + ee;
        xrow[idx] = (e < E_EDGES) ? xn[esrc[e] * DD + q] : 0.f;
    }
    for (int idx = tid; idx < EB * 4; idx += 256) {
        int ee = idx >> 2;
        shl[idx] = (e0 + ee < E_EDGES) ? esh[e0 * 4 + idx] : 0.f;
    }
    for (int idx = tid; idx < EB; idx += 256) {
        int e = e0 + idx;
        ewl[idx] = (e < E_EDGES) ? ewg[e] : 0.f;
        dstl[idx] = (e < E_EDGES) ? edst[e] : 0;
    }
    __syncthreads();
    int wv = __builtin_amdgcn_readfirstlane(tid >> 6);
    int lane = tid & 63;
    int eb = wv * TE;

    int hb[TE];  // wave-uniform -> SGPRs
#pragma unroll
    for (int e = 0; e < TE; e++) {
        int ge = e0 + eb + e;
        if (ge >= E_EDGES) ge = E_EDGES - 1;
        hb[e] = ge * HID;
    }
    float S[TE], B3[TE], V0[TE], V1[TE], V2[TE];
#pragma unroll
    for (int e = 0; e < TE; e++) { S[e] = 0.f; B3[e] = 0.f; V0[e] = 0.f; V1[e] = 0.f; V2[e] = 0.f; }

    const float A1f = 0.125f;                 // 1/sqrt(2*NS)
    const float A2f = 0.17677669529663687f;   // 1/sqrt(2*NV)
    const float A3f = 0.125f;
    const float A4f = 0.17677669529663687f;
    const float IS3 = 0.5773502691896258f;

    for (int pass = 0; pass < 6; ++pass) {
        int J0 = pass * 6;
        float t[6][TE];
#pragma unroll
        for (int j = 0; j < 6; j++)
#pragma unroll
            for (int e = 0; e < TE; e++) t[j][e] = 0.f;
        const float* wbase = mw3 + 64 * J0 + lane;
#pragma unroll 4
        for (int k = 0; k < HID; k++) {
            const float* wr = wbase + k * WNUM;
            float w0 = wr[0], w1 = wr[64], w2 = wr[128], w3 = wr[192], w4 = wr[256], w5 = wr[320];
#pragma unroll
            for (int e = 0; e < TE; e++) {
                float h = h2g[hb[e] + k];  // wave-uniform -> s_load
                t[0][e] += h * w0; t[1][e] += h * w1; t[2][e] += h * w2;
                t[3][e] += h * w3; t[4][e] += h * w4; t[5][e] += h * w5;
            }
        }
        // mb3 bias (once per column per edge)
#pragma unroll
        for (int j = 0; j < 6; j++) {
            float bj = mb3[64 * (J0 + j) + lane];
#pragma unroll
            for (int e = 0; e < TE; e++) t[j][e] += bj;
        }
        // contract i-dimension (cross-lane) into owned accumulators
#pragma unroll
        for (int j = 0; j < 6; j++) {
            int J = J0 + j;
            if (J < 16) {               // w1: i = 2J + (lane>>5), o = lane&31
                int i = 2 * J + (lane >> 5);
#pragma unroll
                for (int e = 0; e < TE; e++) {
                    float coef = A1f * shl[(eb + e) * 4] * xrow[(eb + e) * DD + i];
                    float p = coef * t[j][e];
                    p += __shfl_xor(p, 32);
                    S[e] += p;          // valid on lanes<32
                }
            } else if (J < 24) {        // w2
                int i = 2 * (J - 16) + (lane >> 5);
#pragma unroll
                for (int e = 0; e < TE; e++) {
                    const float* vb = &xrow[(eb + e) * DD + NS + 3 * i];
                    const float* s1 = &shl[(eb + e) * 4 + 1];
                    float inner = vb[0] * s1[0] + vb[1] * s1[1] + vb[2] * s1[2];
                    float p = (A2f * IS3 * inner) * t[j][e];
                    p += __shfl_xor(p, 32);
                    S[e] += p;
                }
            } else if (J < 32) {        // w3: i = 4(J-24)+(lane>>4), o = lane&15
                int i = 4 * (J - 24) + (lane >> 4);
#pragma unroll
                for (int e = 0; e < TE; e++) {
                    float p = A3f * xrow[(eb + e) * DD + i] * t[j][e];
                    p += __shfl_xor(p, 16); p += __shfl_xor(p, 32);
                    B3[e] += p;         // valid on lanes<16
                }
            } else {                    // w4
                int i = 4 * (J - 32) + (lane >> 4);
#pragma unroll
                for (int e = 0; e < TE; e++) {
                    const float* vb = &xrow[(eb + e) * DD + NS + 3 * i];
                    float c = A4f * shl[(eb + e) * 4] * t[j][e];
                    float p0 = c * vb[0]; p0 += __shfl_xor(p0, 16); p0 += __shfl_xor(p0, 32); V0[e] += p0;
                    float p1 = c * vb[1]; p1 += __shfl_xor(p1, 16); p1 += __shfl_xor(p1, 32); V1[e] += p1;
                    float p2 = c * vb[2]; p2 += __shfl_xor(p2, 16); p2 += __shfl_xor(p2, 32); V2[e] += p2;
                }
            }
        }
    }
    // epilogue: weight by edge_w and scatter-add into agg
#pragma unroll
    for (int e = 0; e < TE; e++) {
        float ew = ewl[eb + e];
        int d = dstl[eb + e];
        if (lane < NS) atomicAdd(&agg[d * DD + lane], S[e] * ew);
        if (lane < NV) {
            float sx = shl[(eb + e) * 4 + 1], sy = shl[(eb + e) * 4 + 2], sz = shl[(eb + e) * 4 + 3];
            atomicAdd(&agg[d * DD + NS + lane * 3 + 0], (B3[e] * sx + V0[e]) * ew);
            atomicAdd(&agg[d * DD + NS + lane * 3 + 1], (B3[e] * sy + V1[e]) * ew);
            atomicAdd(&agg[d * DD + NS + lane * 3 + 2], (B3[e] * sz + V2[e]) * ew);
        }
    }
}

// ---------------- K4: per-node update (one 64-thread block per node) ------------
__global__ void k_update(
    const float* __restrict__ x, const float* __restrict__ xn,
    const float* __restrict__ agg, const float* __restrict__ den,
    const float* __restrict__ Ws, const float* __restrict__ Wv,
    const float* __restrict__ Us, const float* __restrict__ Uv,
    const float* __restrict__ Ss, const float* __restrict__ Sv,
    const float* __restrict__ rsp, float* __restrict__ out) {
    int n = blockIdx.x, t = threadIdx.x;
    __shared__ float ag[DD];
    __shared__ float xnl[DD];
    __shared__ float sg[NS];
    __shared__ float gt[NV];
    __shared__ float vg[48];
    float idv = 1.0f / fmaxf(den[n], 1e-8f);
    ag[t] = agg[n * DD + t] * idv;
    if (t < 16) ag[64 + t] = agg[n * DD + 64 + t] * idv;
    xnl[t] = xn[n * DD + t];
    if (t < 16) xnl[64 + t] = xn[n * DD + 64 + t];
    __syncthreads();
    const float iqs = 0.17677669529663687f;  // 1/sqrt(32)
    const float iqv = 0.25f;                 // 1/sqrt(16)
    if (t < 48) {
        float acc = 0.f;
#pragma unroll
        for (int i = 0; i < NS; i++) acc += ag[i] * Ws[i * 48 + t];
        acc *= iqs;
        if (t < NS) sg[t] = silu_f(acc);
        else gt[t - NS] = sigm(acc);
    }
    __syncthreads();
    if (t < 48) {
        int o = t / 3, m = t - 3 * o;
        float acc = 0.f;
#pragma unroll
        for (int i = 0; i < NV; i++) acc += ag[NS + 3 * i + m] * Wv[i * NV + o];
        vg[t] = acc * iqv * gt[o];
    }
    __syncthreads();
    float rs = rsp[0];
    if (t < NS) {
        float us = 0.f, ss = 0.f;
#pragma unroll
        for (int i = 0; i < NS; i++) { us += sg[i] * Us[i * NS + t]; ss += xnl[i] * Ss[i * NS + t]; }
        out[n * DD + t] = x[n * DD + t] + rs * ((ss + us) * iqs);
    }
    if (t < 48) {
        int o = t / 3, m = t - 3 * o;
        float uv = 0.f, sv = 0.f;
#pragma unroll
        for (int i = 0; i < NV; i++) { uv += vg[3 * i + m] * Uv[i * NV + o]; sv += xnl[NS + 3 * i + m] * Sv[i * NV + o]; }
        out[n * DD + NS + t] = x[n * DD + NS + t] + rs * ((sv + uv) * iqv);
    }
}

extern "C" void kernel_launch(void* const* d_in, const int* in_sizes, int n_in,
                              void* d_out, int out_size, void* d_ws, size_t ws_size,
                              hipStream_t stream) {
    (void)in_sizes; (void)n_in; (void)out_size; (void)ws_size;
    const float* x    = (const float*)d_in[0];
    const int*   esrc = (const int*)d_in[1];
    const int*   edst = (const int*)d_in[2];
    const float* esh  = (const float*)d_in[3];
    const float* erbf = (const float*)d_in[4];
    const float* elen = (const float*)d_in[5];
    const float* nw   = (const float*)d_in[6];
    const float* nb   = (const float*)d_in[7];
    const float* mw1  = (const float*)d_in[8];
    const float* mb1  = (const float*)d_in[9];
    const float* mw2  = (const float*)d_in[10];
    const float* mb2  = (const float*)d_in[11];
    const float* mw3  = (const float*)d_in[12];
    const float* mb3  = (const float*)d_in[13];
    const float* gw1  = (const float*)d_in[14];
    const float* gb1  = (const float*)d_in[15];
    const float* gw2  = (const float*)d_in[16];
    const float* gb2  = (const float*)d_in[17];
    const float* Ws   = (const float*)d_in[18];
    const float* Wv   = (const float*)d_in[19];
    const float* Us   = (const float*)d_in[20];
    const float* Uv   = (const float*)d_in[21];
    const float* Ss   = (const float*)d_in[22];
    const float* Sv   = (const float*)d_in[23];
    const float* rsp  = (const float*)d_in[24];
    float* out = (float*)d_out;
    float* ws  = (float*)d_ws;

    float* xn  = ws;                 // 256000
    float* agg = ws + 256000;        // 256000
    float* den = ws + 512000;        // 3200
    float* ewg = ws + 515200;        // 50000
    float* h1g = ws + 565200;        // 6400000
    float* h2g = ws + 6965200;       // 6400000  (total 53.5 MB)

    hipMemsetAsync(agg, 0, (256000 + 3200) * sizeof(float), stream);
    k_norm<<<N_NODES, 64, 0, stream>>>(x, nw, nb, xn);
    k_edge_mlp1<<<782, 256, 0, stream>>>(erbf, elen, edst, mw1, mb1, gw1, gb1, gw2, gb2, h1g, ewg, den);
    k_edge_mlp2<<<782, 256, 0, stream>>>(h1g, mw2, mb2, h2g);
    k_msg<<<1250, 256, 0, stream>>>(xn, h2g, ewg, esrc, edst, esh, mw3, mb3, agg);
    k_update<<<N_NODES, 64, 0, stream>>>(x, xn, agg, den, Ws, Wv, Us, Uv, Ss, Sv, rsp, out);
}

// Round 2
// 434.963 us; speedup vs baseline: 1.3798x; 1.3798x over previous
//
#include <hip/hip_runtime.h>
#include <hip/hip_bf16.h>
#include <math.h>

#define N_NODES 3200
#define E_EDGES 50000
#define RBFN 16
#define HID 128
#define NS 32
#define NV 16
#define DD 80
#define WNUM 2304
#define CUTF 5.0f
#define EPSF 1e-8f

#define A1C 0.125f                  // 1/sqrt(2*NS)
#define A2C 0.17677669529663687f    // 1/sqrt(2*NV)
#define A3C 0.125f
#define A4C 0.17677669529663687f
#define ISQ3 0.5773502691896258f
#define A2ISQ 0.10206207261596575f  // A2C * ISQ3

typedef __attribute__((ext_vector_type(4))) float f32x4;
typedef __attribute__((ext_vector_type(8))) short bf16x8;

__device__ __forceinline__ float sigm(float x) { return 1.0f / (1.0f + __expf(-x)); }
__device__ __forceinline__ float silu_f(float x) { return x * sigm(x); }

__device__ __forceinline__ short bf16r(float x) {
    union { float f; unsigned u; } v; v.f = x;
    unsigned r = (v.u + 0x7fffu + ((v.u >> 16) & 1u)) >> 16;
    return (short)r;
}

// ---------------- K0: prep — mw3 -> bf16 [col][k] swizzled + bias frags ---------
// mw3s layout: tile t (16 cols), r=col&15, chunk c (=k/8, 0..15) stored at
//   t*2048 + r*128 + (c ^ r)*8 + (k&7)    (XOR swizzle -> conflict-free ds_read_b128)
__global__ void k_prep(const float* __restrict__ mw3, const float* __restrict__ mb3,
                       __hip_bfloat16* __restrict__ mw3s, __hip_bfloat16* __restrict__ biasf) {
    int b = blockIdx.x, tid = threadIdx.x;
    if (b < 144) {
        int r = tid & 15, c = tid >> 4;
        int col = b * 16 + r;
        int ko = c * 8;
        __hip_bfloat16 tmp[8];
#pragma unroll
        for (int j = 0; j < 8; j++) tmp[j] = __float2bfloat16(mw3[(ko + j) * WNUM + col]);
        __hip_bfloat16* dst = mw3s + b * 2048 + r * 128 + (c ^ r) * 8;
#pragma unroll
        for (int j = 0; j < 8; j++) dst[j] = tmp[j];
    } else {
        // bias A-frags (A[m=lane&15][k=(lane>>4)*8+j]) for the 4 regions
        for (int idx = tid; idx < 3072; idx += 256) {
            float val;
            if (idx < 1024) {                 // region1: mb3[i*32 + o], o = oh*16+m
                int oh = idx >> 9, l = (idx >> 3) & 63, j = idx & 7;
                int o = oh * 16 + (l & 15), i = (l >> 4) * 8 + j;
                val = mb3[i * 32 + o];
            } else if (idx < 2048) {          // region2 (i<16)
                int t = idx - 1024;
                int oh = t >> 9, l = (t >> 3) & 63, j = t & 7;
                int o = oh * 16 + (l & 15), i = (l >> 4) * 8 + j;
                val = (i < 16) ? mb3[1024 + i * 32 + o] : 0.f;
            } else if (idx < 2560) {          // region3
                int t = idx - 2048;
                int l = t >> 3, j = t & 7;
                int o = l & 15, i = (l >> 4) * 8 + j;
                val = mb3[1536 + i * 16 + o];
            } else {                          // region4 (i<16)
                int t = idx - 2560;
                int l = t >> 3, j = t & 7;
                int o = l & 15, i = (l >> 4) * 8 + j;
                val = (i < 16) ? mb3[2048 + i * 16 + o] : 0.f;
            }
            biasf[idx] = __float2bfloat16(val);
        }
    }
}

// ---------------- K1: irrep norm  (one 64-thread block per node) ----------------
__global__ void k_norm(const float* __restrict__ x, const float* __restrict__ nw,
                       const float* __restrict__ nb, float* __restrict__ xn) {
    int n = blockIdx.x, t = threadIdx.x;
    __shared__ float row[DD];
    const float* xr = x + n * DD;
    row[t] = xr[t];
    if (t < DD - 64) row[64 + t] = xr[64 + t];
    __syncthreads();
    float mean = 0.f;
#pragma unroll
    for (int i = 0; i < NS; i++) mean += row[i];
    mean *= (1.0f / NS);
    float var = 0.f;
#pragma unroll
    for (int i = 0; i < NS; i++) { float d = row[i] - mean; var += d * d; }
    var *= (1.0f / NS);
    float inv = rsqrtf(var + EPSF);
    if (t < NS) {
        float v = (row[t] - mean) * inv;
        xn[n * DD + t] = v * nw[t] + nb[t];
    }
    if (t < 48) {
        int j = t / 3;
        float v0 = row[NS + 3 * j], v1 = row[NS + 3 * j + 1], v2 = row[NS + 3 * j + 2];
        float rms = sqrtf((v0 * v0 + v1 * v1 + v2 * v2) * (1.0f / 3.0f) + EPSF);
        float v = row[NS + t] / rms;
        xn[n * DD + NS + t] = v * nw[NS + t] + nb[NS + t];
    }
}

// ------------- K2a: edge MLP layer 1 + gate + cutoff + den atomic ---------------
__global__ __launch_bounds__(256) void k_edge_mlp1(
    const float* __restrict__ rbf, const float* __restrict__ elen,
    const int* __restrict__ dst,
    const float* __restrict__ mw1, const float* __restrict__ mb1,
    const float* __restrict__ gw1, const float* __restrict__ gb1,
    const float* __restrict__ gw2, const float* __restrict__ gb2,
    float* __restrict__ h1g, float* __restrict__ ewg, float* __restrict__ den) {
    int wv = __builtin_amdgcn_readfirstlane(threadIdx.x >> 6) + blockIdx.x * 4;
    int lane = threadIdx.x & 63;
    int eb = wv * 16;
    if (eb >= E_EDGES) return;
    int c0 = lane, c1 = 64 + lane;
    float t0[16], t1[16], g0[16], g1[16];
    float b0 = mb1[c0], b1 = mb1[c1], gb0v = gb1[c0], gb1v = gb1[c1];
#pragma unroll
    for (int e = 0; e < 16; e++) { t0[e] = b0; t1[e] = b1; g0[e] = gb0v; g1[e] = gb1v; }
#pragma unroll
    for (int r = 0; r < RBFN; r++) {
        float w0 = mw1[r * HID + c0], w1 = mw1[r * HID + c1];
        float v0 = gw1[r * HID + c0], v1 = gw1[r * HID + c1];
#pragma unroll
        for (int e = 0; e < 16; e++) {
            float rv = rbf[(eb + e) * RBFN + r];
            t0[e] += rv * w0; t1[e] += rv * w1;
            g0[e] += rv * v0; g1[e] += rv * v1;
        }
    }
    float q0 = gw2[c0], q1 = gw2[c1];
    float gb2v = gb2[0];
#pragma unroll
    for (int e = 0; e < 16; e++) {
        h1g[(eb + e) * HID + c0] = silu_f(t0[e]);
        h1g[(eb + e) * HID + c1] = silu_f(t1[e]);
        float p = silu_f(g0[e]) * q0 + silu_f(g1[e]) * q1;
        p += __shfl_xor(p, 1);  p += __shfl_xor(p, 2);  p += __shfl_xor(p, 4);
        p += __shfl_xor(p, 8);  p += __shfl_xor(p, 16); p += __shfl_xor(p, 32);
        if (lane == 0) {
            float len = elen[eb + e];
            float cut = (len <= CUTF) ? 0.5f * (cosf(3.14159265358979f * len / CUTF) + 1.0f) : 0.f;
            float ew = cut * sigm(p + gb2v);
            ewg[eb + e] = ew;
            atomicAdd(&den[dst[eb + e]], ew);
        }
    }
}

// ---------------- K2b: edge MLP layer 2 (128x128) -> h2 in bf16 -----------------
__global__ __launch_bounds__(256) void k_edge_mlp2(
    const float* __restrict__ h1g, const float* __restrict__ mw2,
    const float* __restrict__ mb2, __hip_bfloat16* __restrict__ h2b) {
    int wv = __builtin_amdgcn_readfirstlane(threadIdx.x >> 6) + blockIdx.x * 4;
    int lane = threadIdx.x & 63;
    int eb = wv * 16;
    if (eb >= E_EDGES) return;
    int c0 = lane, c1 = 64 + lane;
    float t0[16], t1[16];
    float b0 = mb2[c0], b1 = mb2[c1];
#pragma unroll
    for (int e = 0; e < 16; e++) { t0[e] = b0; t1[e] = b1; }
#pragma unroll 4
    for (int k = 0; k < HID; k++) {
        float w0 = mw2[k * HID + c0], w1 = mw2[k * HID + c1];
#pragma unroll
        for (int e = 0; e < 16; e++) {
            float h = h1g[(eb + e) * HID + k];
            t0[e] += h * w0; t1[e] += h * w1;
        }
    }
#pragma unroll
    for (int e = 0; e < 16; e++) {
        h2b[(eb + e) * HID + c0] = __float2bfloat16(silu_f(t0[e]));
        h2b[(eb + e) * HID + c1] = __float2bfloat16(silu_f(t1[e]));
    }
}

// -------- K3: fused bf16-MFMA tpw GEMM + tensor-product messages + scatter ------
// WG = 128 thr (2 waves), 64 edges/WG; wave owns 32 edges (2 et-groups of 16).
// 144 column tiles (16 cols each), chunk = 2 tiles, dbuf LDS, 1 barrier/chunk.
__global__ __launch_bounds__(128) void k_msg(
    const float* __restrict__ xn, const __hip_bfloat16* __restrict__ h2b,
    const float* __restrict__ ewg, const int* __restrict__ esrc,
    const int* __restrict__ edst, const float* __restrict__ esh,
    const __hip_bfloat16* __restrict__ mw3s, const __hip_bfloat16* __restrict__ biasf,
    float* __restrict__ agg) {
    __shared__ __hip_bfloat16 bufA[2][4096];   // 2 x 8KB (2 tiles per chunk)
    __shared__ float xng[64][84];              // gathered x_norm rows (pad 84)
    __shared__ float innr[64][36];             // A2*ISQ3 * inner (pad 36, zero-filled)
    __shared__ float sh1l[64][4];
    __shared__ float sh0l[64], ewl[64];
    __shared__ int dstl[64], srcl[64];

    const int tid = threadIdx.x;
    const int wid = __builtin_amdgcn_readfirstlane(tid >> 6);
    const int lane = tid & 63;
    const int q4 = lane >> 4;       // 0..3
    const int l15 = lane & 15;
    const int ib = q4 * 8;
    const int e0 = blockIdx.x * 64;

    if (tid < 64) {
        int ge = e0 + tid;
        bool v = ge < E_EDGES;
        if (!v) ge = E_EDGES - 1;
        srcl[tid] = esrc[ge];
        dstl[tid] = edst[ge];
        ewl[tid] = v ? ewg[ge] : 0.f;
        sh0l[tid] = esh[ge * 4];
        sh1l[tid][0] = esh[ge * 4 + 1];
        sh1l[tid][1] = esh[ge * 4 + 2];
        sh1l[tid][2] = esh[ge * 4 + 3];
    }
    for (int idx = tid; idx < 64 * 36; idx += 128) ((float*)innr)[idx] = 0.f;
    __syncthreads();
    for (int idx = tid; idx < 64 * 80; idx += 128) {
        int e = idx / 80, q = idx - e * 80;
        xng[e][q] = xn[srcl[e] * 80 + q];
    }
    __syncthreads();
    for (int idx = tid; idx < 64 * 16; idx += 128) {
        int e = idx >> 4, i = idx & 15;
        const float* vb = &xng[e][32 + 3 * i];
        innr[e][i] = A2ISQ * (vb[0] * sh1l[e][0] + vb[1] * sh1l[e][1] + vb[2] * sh1l[e][2]);
    }
    __syncthreads();

    // ---------------- per-wave prologue: fragments ----------------
    int el[2] = { wid * 32 + l15, wid * 32 + 16 + l15 };
    float f1[2], f4e[2];
    bf16x8 hfr[2][4], p1f[2], p2f[2], xsf[2], xvf[3][2];
#pragma unroll
    for (int et = 0; et < 2; et++) {
        f1[et] = A1C * sh0l[el[et]];
        f4e[et] = A4C * sh0l[el[et]];
        int ge = e0 + el[et];
        if (ge >= E_EDGES) ge = E_EDGES - 1;
        const __hip_bfloat16* hr = h2b + ge * 128;
#pragma unroll
        for (int kk = 0; kk < 4; kk++)
            hfr[et][kk] = *(const bf16x8*)(hr + kk * 32 + ib);
        const float* xr = &xng[el[et]][0];
        bf16x8 xs8, p18, p28;
#pragma unroll
        for (int j = 0; j < 8; j++) {
            float xv_ = xr[ib + j];
            xs8[j] = bf16r(xv_);
            p18[j] = bf16r(xv_ * f1[et]);
            p28[j] = bf16r(innr[el[et]][ib + j]);
        }
        xsf[et] = xs8; p1f[et] = p18; p2f[et] = p28;
#pragma unroll
        for (int m = 0; m < 3; m++) {
            bf16x8 t8;
#pragma unroll
            for (int j = 0; j < 8; j++) {
                int i = ib + j;
                float v = (i < 16) ? xr[32 + 3 * i + m] : 0.f;
                t8[j] = bf16r(v);
            }
            xvf[m][et] = t8;
        }
    }
    bf16x8 ba1[2], ba2[2], ba3, ba4;
    ba1[0] = *(const bf16x8*)(biasf + lane * 8);
    ba1[1] = *(const bf16x8*)(biasf + 512 + lane * 8);
    ba2[0] = *(const bf16x8*)(biasf + 1024 + lane * 8);
    ba2[1] = *(const bf16x8*)(biasf + 1536 + lane * 8);
    ba3    = *(const bf16x8*)(biasf + 2048 + lane * 8);
    ba4    = *(const bf16x8*)(biasf + 2560 + lane * 8);

    const f32x4 zf = {0.f, 0.f, 0.f, 0.f};
    f32x4 msgS[2][2], q3[2], qv[3][2];   // [ohalf][et], [et], [m][et]
#pragma unroll
    for (int et = 0; et < 2; et++) {
#pragma unroll
        for (int oh = 0; oh < 2; oh++) {
            f32x4 a = __builtin_amdgcn_mfma_f32_16x16x32_bf16(ba1[oh], p1f[et], zf, 0, 0, 0);
            msgS[oh][et] = __builtin_amdgcn_mfma_f32_16x16x32_bf16(ba2[oh], p2f[et], a, 0, 0, 0);
        }
        q3[et] = __builtin_amdgcn_mfma_f32_16x16x32_bf16(ba3, xsf[et], zf, 0, 0, 0);
#pragma unroll
        for (int m = 0; m < 3; m++)
            qv[m][et] = __builtin_amdgcn_mfma_f32_16x16x32_bf16(ba4, xvf[m][et], zf, 0, 0, 0);
    }

    // ---------------- main loop: 72 chunks x 2 tiles ----------------
    const f32x4* gsrc = (const f32x4*)mw3s;   // 16B units
    f32x4* lbuf0 = (f32x4*)bufA[0];
    f32x4* lbuf1 = (f32x4*)bufA[1];
    f32x4 ldg[4];
#pragma unroll
    for (int i = 0; i < 4; i++) ldg[i] = gsrc[tid + i * 128];
#pragma unroll
    for (int i = 0; i < 4; i++) lbuf0[tid + i * 128] = ldg[i];
#pragma unroll
    for (int i = 0; i < 4; i++) ldg[i] = gsrc[512 + tid + i * 128];

    for (int n = 0; n < 72; n++) {
        __syncthreads();
        if (n + 1 < 72) {
            f32x4* lb = ((n + 1) & 1) ? lbuf1 : lbuf0;
#pragma unroll
            for (int i = 0; i < 4; i++) lb[tid + i * 128] = ldg[i];
            if (n + 2 < 72) {
#pragma unroll
                for (int i = 0; i < 4; i++) ldg[i] = gsrc[(n + 2) * 512 + tid + i * 128];
            }
        }
        const __hip_bfloat16* bb = bufA[n & 1];
        f32x4 acc[2][2];
#pragma unroll
        for (int half = 0; half < 2; half++) {
            bf16x8 af[4];
#pragma unroll
            for (int kk = 0; kk < 4; kk++) {
                int cc = (kk * 4 + q4) ^ l15;
                af[kk] = *(const bf16x8*)(bb + half * 2048 + l15 * 128 + cc * 8);
            }
            f32x4 a0 = zf, a1 = zf;
#pragma unroll
            for (int kk = 0; kk < 4; kk++) {
                a0 = __builtin_amdgcn_mfma_f32_16x16x32_bf16(af[kk], hfr[0][kk], a0, 0, 0, 0);
                a1 = __builtin_amdgcn_mfma_f32_16x16x32_bf16(af[kk], hfr[1][kk], a1, 0, 0, 0);
            }
            acc[half][0] = a0; acc[half][1] = a1;
        }
        if (n < 32) {              // w1: i = n, ohalf = half
            float p0 = f1[0] * xng[el[0]][n];
            float p1 = f1[1] * xng[el[1]][n];
#pragma unroll
            for (int half = 0; half < 2; half++)
#pragma unroll
                for (int r = 0; r < 4; r++) {
                    msgS[half][0][r] += p0 * acc[half][0][r];
                    msgS[half][1][r] += p1 * acc[half][1][r];
                }
        } else if (n < 48) {       // w2: i = n-32 (innr pre-scaled)
            float p0 = innr[el[0]][n - 32];
            float p1 = innr[el[1]][n - 32];
#pragma unroll
            for (int half = 0; half < 2; half++)
#pragma unroll
                for (int r = 0; r < 4; r++) {
                    msgS[half][0][r] += p0 * acc[half][0][r];
                    msgS[half][1][r] += p1 * acc[half][1][r];
                }
        } else if (n < 64) {       // w3: i = 2*(n-48)+half (A3 folded at end)
#pragma unroll
            for (int half = 0; half < 2; half++) {
                int i = 2 * (n - 48) + half;
                float p0 = xng[el[0]][i];
                float p1 = xng[el[1]][i];
#pragma unroll
                for (int r = 0; r < 4; r++) {
                    q3[0][r] += p0 * acc[half][0][r];
                    q3[1][r] += p1 * acc[half][1][r];
                }
            }
        } else {                   // w4: i = 2*(n-64)+half (A4*sh0 folded at end)
#pragma unroll
            for (int half = 0; half < 2; half++) {
                int i = 2 * (n - 64) + half;
#pragma unroll
                for (int m = 0; m < 3; m++) {
                    float p0 = xng[el[0]][32 + 3 * i + m];
                    float p1 = xng[el[1]][32 + 3 * i + m];
#pragma unroll
                    for (int r = 0; r < 4; r++) {
                        qv[m][0][r] += p0 * acc[half][0][r];
                        qv[m][1][r] += p1 * acc[half][1][r];
                    }
                }
            }
        }
    }

    // ---------------- epilogue: weight + scatter-add ----------------
#pragma unroll
    for (int et = 0; et < 2; et++) {
        int le = el[et];
        float ew = ewl[le];
        int d = dstl[le];
        float s0 = sh1l[le][0], s1 = sh1l[le][1], s2 = sh1l[le][2];
        float b4 = f4e[et];
        float* ag = agg + d * 80;
        int ob = q4 * 4;
#pragma unroll
        for (int r = 0; r < 4; r++) {
            int o = ob + r;
            atomicAdd(ag + o, msgS[0][et][r] * ew);
            atomicAdd(ag + 16 + o, msgS[1][et][r] * ew);
            float qq = A3C * q3[et][r];
            atomicAdd(ag + 32 + o * 3 + 0, (qq * s0 + b4 * qv[0][et][r]) * ew);
            atomicAdd(ag + 32 + o * 3 + 1, (qq * s1 + b4 * qv[1][et][r]) * ew);
            atomicAdd(ag + 32 + o * 3 + 2, (qq * s2 + b4 * qv[2][et][r]) * ew);
        }
    }
}

// ---------------- K4: per-node update (one 64-thread block per node) ------------
__global__ void k_update(
    const float* __restrict__ x, const float* __restrict__ xn,
    const float* __restrict__ agg, const float* __restrict__ den,
    const float* __restrict__ Ws, const float* __restrict__ Wv,
    const float* __restrict__ Us, const float* __restrict__ Uv,
    const float* __restrict__ Ss, const float* __restrict__ Sv,
    const float* __restrict__ rsp, float* __restrict__ out) {
    int n = blockIdx.x, t = threadIdx.x;
    __shared__ float ag[DD];
    __shared__ float xnl[DD];
    __shared__ float sg[NS];
    __shared__ float gt[NV];
    __shared__ float vg[48];
    float idv = 1.0f / fmaxf(den[n], 1e-8f);
    ag[t] = agg[n * DD + t] * idv;
    if (t < 16) ag[64 + t] = agg[n * DD + 64 + t] * idv;
    xnl[t] = xn[n * DD + t];
    if (t < 16) xnl[64 + t] = xn[n * DD + 64 + t];
    __syncthreads();
    const float iqs = 0.17677669529663687f;
    const float iqv = 0.25f;
    if (t < 48) {
        float acc = 0.f;
#pragma unroll
        for (int i = 0; i < NS; i++) acc += ag[i] * Ws[i * 48 + t];
        acc *= iqs;
        if (t < NS) sg[t] = silu_f(acc);
        else gt[t - NS] = sigm(acc);
    }
    __syncthreads();
    if (t < 48) {
        int o = t / 3, m = t - 3 * o;
        float acc = 0.f;
#pragma unroll
        for (int i = 0; i < NV; i++) acc += ag[NS + 3 * i + m] * Wv[i * NV + o];
        vg[t] = acc * iqv * gt[o];
    }
    __syncthreads();
    float rs = rsp[0];
    if (t < NS) {
        float us = 0.f, ss = 0.f;
#pragma unroll
        for (int i = 0; i < NS; i++) { us += sg[i] * Us[i * NS + t]; ss += xnl[i] * Ss[i * NS + t]; }
        out[n * DD + t] = x[n * DD + t] + rs * ((ss + us) * iqs);
    }
    if (t < 48) {
        int o = t / 3, m = t - 3 * o;
        float uv = 0.f, sv = 0.f;
#pragma unroll
        for (int i = 0; i < NV; i++) { uv += vg[3 * i + m] * Uv[i * NV + o]; sv += xnl[NS + 3 * i + m] * Sv[i * NV + o]; }
        out[n * DD + NS + t] = x[n * DD + NS + t] + rs * ((sv + uv) * iqv);
    }
}

extern "C" void kernel_launch(void* const* d_in, const int* in_sizes, int n_in,
                              void* d_out, int out_size, void* d_ws, size_t ws_size,
                              hipStream_t stream) {
    (void)in_sizes; (void)n_in; (void)out_size; (void)ws_size;
    const float* x    = (const float*)d_in[0];
    const int*   esrc = (const int*)d_in[1];
    const int*   edst = (const int*)d_in[2];
    const float* esh  = (const float*)d_in[3];
    const float* erbf = (const float*)d_in[4];
    const float* elen = (const float*)d_in[5];
    const float* nw   = (const float*)d_in[6];
    const float* nb   = (const float*)d_in[7];
    const float* mw1  = (const float*)d_in[8];
    const float* mb1  = (const float*)d_in[9];
    const float* mw2  = (const float*)d_in[10];
    const float* mb2  = (const float*)d_in[11];
    const float* mw3  = (const float*)d_in[12];
    const float* mb3  = (const float*)d_in[13];
    const float* gw1  = (const float*)d_in[14];
    const float* gb1  = (const float*)d_in[15];
    const float* gw2  = (const float*)d_in[16];
    const float* gb2  = (const float*)d_in[17];
    const float* Ws   = (const float*)d_in[18];
    const float* Wv   = (const float*)d_in[19];
    const float* Us   = (const float*)d_in[20];
    const float* Uv   = (const float*)d_in[21];
    const float* Ss   = (const float*)d_in[22];
    const float* Sv   = (const float*)d_in[23];
    const float* rsp  = (const float*)d_in[24];
    float* out = (float*)d_out;
    float* ws  = (float*)d_ws;

    float* xn  = ws;                          // 256000 f32
    float* agg = ws + 256000;                 // 256000 f32
    float* den = ws + 512000;                 // 3200 f32
    float* ewg = ws + 515200;                 // 50000 f32
    float* h1g = ws + 565200;                 // 6,400,000 f32 (ends 6,965,200)
    __hip_bfloat16* h2b  = (__hip_bfloat16*)(ws + 6965200);            // 6.4M bf16
    __hip_bfloat16* mw3s = (__hip_bfloat16*)((char*)d_ws + 40660800);  // 294912 bf16
    __hip_bfloat16* bias = (__hip_bfloat16*)((char*)d_ws + 41250624);  // 3072 bf16

    hipMemsetAsync(agg, 0, (256000 + 3200) * sizeof(float), stream);
    k_prep<<<145, 256, 0, stream>>>(mw3, mb3, mw3s, bias);
    k_norm<<<N_NODES, 64, 0, stream>>>(x, nw, nb, xn);
    k_edge_mlp1<<<782, 256, 0, stream>>>(erbf, elen, edst, mw1, mb1, gw1, gb1, gw2, gb2, h1g, ewg, den);
    k_edge_mlp2<<<782, 256, 0, stream>>>(h1g, mw2, mb2, h2b);
    k_msg<<<782, 128, 0, stream>>>(xn, h2b, ewg, esrc, edst, esh, mw3s, bias, agg);
    k_update<<<N_NODES, 64, 0, stream>>>(x, xn, agg, den, Ws, Wv, Us, Uv, Ss, Sv, rsp, out);
}

// Round 3
// 371.097 us; speedup vs baseline: 1.6173x; 1.1721x over previous
//
#include <hip/hip_runtime.h>
#include <hip/hip_bf16.h>
#include <math.h>

#define N_NODES 3200
#define E_EDGES 50000
#define RBFN 16
#define HID 128
#define NS 32
#define NV 16
#define DD 80
#define WNUM 2304
#define CUTF 5.0f
#define EPSF 1e-8f

#define A1C 0.125f                  // 1/sqrt(2*NS)
#define A2C 0.17677669529663687f    // 1/sqrt(2*NV)
#define A3C 0.125f
#define A4C 0.17677669529663687f
#define ISQ3 0.5773502691896258f
#define A2ISQ 0.10206207261596575f  // A2C * ISQ3

typedef __attribute__((ext_vector_type(4))) float f32x4;
typedef __attribute__((ext_vector_type(8))) short bf16x8;

__device__ __forceinline__ float sigm(float x) { return 1.0f / (1.0f + __expf(-x)); }
__device__ __forceinline__ float silu_f(float x) { return x * sigm(x); }

__device__ __forceinline__ short bf16r(float x) {
    union { float f; unsigned u; } v; v.f = x;
    unsigned r = (v.u + 0x7fffu + ((v.u >> 16) & 1u)) >> 16;
    return (short)r;
}

// ---------------- K0: prep — frag-linear bf16 images of mw3 / mw2 + bias frags --
// Fragment convention (m97/m89-verified): A-frag for 16x16x32: lane = q4*16+l15
// holds A[m=l15][k=q4*8+j], j=0..7. Tile = 16 cols x 128 k = 2048 bf16, stored
// contiguous: tile*2048 + kk*512 + lane*8 + j   (kk = k/32).
__global__ void k_prep(const float* __restrict__ mw3, const float* __restrict__ mw2,
                       const float* __restrict__ mb3,
                       __hip_bfloat16* __restrict__ mw3f, __hip_bfloat16* __restrict__ mw2f,
                       __hip_bfloat16* __restrict__ biasf) {
    __shared__ __hip_bfloat16 st[2048];
    int b = blockIdx.x, tid = threadIdx.x;
    if (b < 152) {
        bool is3 = b < 144;
        int t = is3 ? b : (b - 144);
        for (int idx = tid; idx < 2048; idx += 256) {
            int k = idx >> 4, c = idx & 15;
            float v = is3 ? mw3[k * WNUM + t * 16 + c] : mw2[k * HID + t * 16 + c];
            int kk = k >> 5, q4 = (k >> 3) & 3, j = k & 7;
            st[kk * 512 + (q4 * 16 + c) * 8 + j] = __float2bfloat16(v);
        }
        __syncthreads();
        __hip_bfloat16* dst = is3 ? (mw3f + t * 2048) : (mw2f + t * 2048);
        ((bf16x8*)dst)[tid] = ((const bf16x8*)st)[tid];
    } else {
        // bias A-frags (A[m=lane&15][k=(lane>>4)*8+j]) for the 4 regions
        for (int idx = tid; idx < 3072; idx += 256) {
            float val;
            if (idx < 1024) {                 // region1: mb3[i*32 + o], o = oh*16+m
                int oh = idx >> 9, l = (idx >> 3) & 63, j = idx & 7;
                int o = oh * 16 + (l & 15), i = (l >> 4) * 8 + j;
                val = mb3[i * 32 + o];
            } else if (idx < 2048) {          // region2 (i<16)
                int t = idx - 1024;
                int oh = t >> 9, l = (t >> 3) & 63, j = t & 7;
                int o = oh * 16 + (l & 15), i = (l >> 4) * 8 + j;
                val = (i < 16) ? mb3[1024 + i * 32 + o] : 0.f;
            } else if (idx < 2560) {          // region3
                int t = idx - 2048;
                int l = t >> 3, j = t & 7;
                int o = l & 15, i = (l >> 4) * 8 + j;
                val = mb3[1536 + i * 16 + o];
            } else {                          // region4 (i<16)
                int t = idx - 2560;
                int l = t >> 3, j = t & 7;
                int o = l & 15, i = (l >> 4) * 8 + j;
                val = (i < 16) ? mb3[2048 + i * 16 + o] : 0.f;
            }
            biasf[idx] = __float2bfloat16(val);
        }
    }
}

// ---------------- K1: irrep norm  (one 64-thread block per node) ----------------
__global__ void k_norm(const float* __restrict__ x, const float* __restrict__ nw,
                       const float* __restrict__ nb, float* __restrict__ xn) {
    int n = blockIdx.x, t = threadIdx.x;
    __shared__ float row[DD];
    const float* xr = x + n * DD;
    row[t] = xr[t];
    if (t < DD - 64) row[64 + t] = xr[64 + t];
    __syncthreads();
    float mean = 0.f;
#pragma unroll
    for (int i = 0; i < NS; i++) mean += row[i];
    mean *= (1.0f / NS);
    float var = 0.f;
#pragma unroll
    for (int i = 0; i < NS; i++) { float d = row[i] - mean; var += d * d; }
    var *= (1.0f / NS);
    float inv = rsqrtf(var + EPSF);
    if (t < NS) {
        float v = (row[t] - mean) * inv;
        xn[n * DD + t] = v * nw[t] + nb[t];
    }
    if (t < 48) {
        int j = t / 3;
        float v0 = row[NS + 3 * j], v1 = row[NS + 3 * j + 1], v2 = row[NS + 3 * j + 2];
        float rms = sqrtf((v0 * v0 + v1 * v1 + v2 * v2) * (1.0f / 3.0f) + EPSF);
        float v = row[NS + t] / rms;
        xn[n * DD + NS + t] = v * nw[NS + t] + nb[NS + t];
    }
}

// ------------- K2a: edge MLP layer 1 + gate + cutoff + den atomic ---------------
__global__ __launch_bounds__(256) void k_edge_mlp1(
    const float* __restrict__ rbf, const float* __restrict__ elen,
    const int* __restrict__ dst,
    const float* __restrict__ mw1, const float* __restrict__ mb1,
    const float* __restrict__ gw1, const float* __restrict__ gb1,
    const float* __restrict__ gw2, const float* __restrict__ gb2,
    __hip_bfloat16* __restrict__ h1b, float* __restrict__ ewg, float* __restrict__ den) {
    int wv = __builtin_amdgcn_readfirstlane(threadIdx.x >> 6) + blockIdx.x * 4;
    int lane = threadIdx.x & 63;
    int eb = wv * 16;
    if (eb >= E_EDGES) return;
    int c0 = lane, c1 = 64 + lane;
    float t0[16], t1[16], g0[16], g1[16];
    float b0 = mb1[c0], b1 = mb1[c1], gb0v = gb1[c0], gb1v = gb1[c1];
#pragma unroll
    for (int e = 0; e < 16; e++) { t0[e] = b0; t1[e] = b1; g0[e] = gb0v; g1[e] = gb1v; }
#pragma unroll
    for (int r = 0; r < RBFN; r++) {
        float w0 = mw1[r * HID + c0], w1 = mw1[r * HID + c1];
        float v0 = gw1[r * HID + c0], v1 = gw1[r * HID + c1];
#pragma unroll
        for (int e = 0; e < 16; e++) {
            float rv = rbf[(eb + e) * RBFN + r];
            t0[e] += rv * w0; t1[e] += rv * w1;
            g0[e] += rv * v0; g1[e] += rv * v1;
        }
    }
    float q0 = gw2[c0], q1 = gw2[c1];
    float gb2v = gb2[0];
#pragma unroll
    for (int e = 0; e < 16; e++) {
        h1b[(eb + e) * HID + c0] = __float2bfloat16(silu_f(t0[e]));
        h1b[(eb + e) * HID + c1] = __float2bfloat16(silu_f(t1[e]));
        float p = silu_f(g0[e]) * q0 + silu_f(g1[e]) * q1;
        p += __shfl_xor(p, 1);  p += __shfl_xor(p, 2);  p += __shfl_xor(p, 4);
        p += __shfl_xor(p, 8);  p += __shfl_xor(p, 16); p += __shfl_xor(p, 32);
        if (lane == 0) {
            float len = elen[eb + e];
            float cut = (len <= CUTF) ? 0.5f * (cosf(3.14159265358979f * len / CUTF) + 1.0f) : 0.f;
            float ew = cut * sigm(p + gb2v);
            ewg[eb + e] = ew;
            atomicAdd(&den[dst[eb + e]], ew);
        }
    }
}

// ---------------- K2b: edge MLP layer 2 as bf16 MFMA (128x128 GEMM) -------------
// Wave: 32 edges (2 et of 16) x 128 cols (8 col-tiles). mw2f is 32KB, L1-resident.
__global__ __launch_bounds__(256) void k_mlp2(
    const __hip_bfloat16* __restrict__ h1b, const __hip_bfloat16* __restrict__ mw2f,
    const float* __restrict__ mb2, __hip_bfloat16* __restrict__ h2b) {
    int tid = threadIdx.x;
    int wid = __builtin_amdgcn_readfirstlane(tid >> 6);
    int lane = tid & 63, q4 = lane >> 4, l15 = lane & 15;
    int base = blockIdx.x * 128 + wid * 32;
    bf16x8 af[2][4];
#pragma unroll
    for (int et = 0; et < 2; et++) {
        int ge = base + et * 16 + l15;
        if (ge >= E_EDGES) ge = E_EDGES - 1;
#pragma unroll
        for (int kk = 0; kk < 4; kk++)
            af[et][kk] = *(const bf16x8*)(h1b + ge * HID + kk * 32 + q4 * 8);
    }
    const f32x4 zf = {0.f, 0.f, 0.f, 0.f};
    f32x4 acc[8][2];
#pragma unroll
    for (int ct = 0; ct < 8; ct++) { acc[ct][0] = zf; acc[ct][1] = zf; }
#pragma unroll
    for (int ct = 0; ct < 8; ct++) {
#pragma unroll
        for (int kk = 0; kk < 4; kk++) {
            bf16x8 bw = *(const bf16x8*)(mw2f + (ct * 4 + kk) * 512 + lane * 8);
            acc[ct][0] = __builtin_amdgcn_mfma_f32_16x16x32_bf16(af[0][kk], bw, acc[ct][0], 0, 0, 0);
            acc[ct][1] = __builtin_amdgcn_mfma_f32_16x16x32_bf16(af[1][kk], bw, acc[ct][1], 0, 0, 0);
        }
    }
#pragma unroll
    for (int ct = 0; ct < 8; ct++) {
        float bias = mb2[ct * 16 + l15];
#pragma unroll
        for (int et = 0; et < 2; et++) {
#pragma unroll
            for (int r = 0; r < 4; r++) {
                int ge = base + et * 16 + q4 * 4 + r;
                if (ge < E_EDGES)
                    h2b[ge * HID + ct * 16 + l15] = __float2bfloat16(silu_f(acc[ct][et][r] + bias));
            }
        }
    }
}

// -------- K3: fused bf16-MFMA tpw GEMM + tensor-product messages + scatter ------
// WG = 128 thr (2 waves), 64 edges/WG; wave owns 32 edges (2 et of 16).
// NO main-loop barriers: A-frags loaded directly from frag-linear mw3f (global),
// register double-buffered, 72 chunks of 32 cols x 128 k.
__global__ __launch_bounds__(128) void k_msg(
    const float* __restrict__ xn, const __hip_bfloat16* __restrict__ h2b,
    const float* __restrict__ ewg, const int* __restrict__ esrc,
    const int* __restrict__ edst, const float* __restrict__ esh,
    const __hip_bfloat16* __restrict__ mw3f, const __hip_bfloat16* __restrict__ biasf,
    float* __restrict__ agg) {
    __shared__ float xng[64][84];
    __shared__ float innr[64][17];
    __shared__ float sh1l[64][4];
    __shared__ float sh0l[64], ewl[64];
    __shared__ int dstl[64], srcl[64];

    const int tid = threadIdx.x;
    const int wid = __builtin_amdgcn_readfirstlane(tid >> 6);
    const int lane = tid & 63;
    const int q4 = lane >> 4;
    const int l15 = lane & 15;
    const int ib = q4 * 8;
    const int e0 = blockIdx.x * 64;

    if (tid < 64) {
        int ge = e0 + tid;
        bool v = ge < E_EDGES;
        if (!v) ge = E_EDGES - 1;
        srcl[tid] = esrc[ge];
        dstl[tid] = edst[ge];
        ewl[tid] = v ? ewg[ge] : 0.f;
        sh0l[tid] = esh[ge * 4];
        sh1l[tid][0] = esh[ge * 4 + 1];
        sh1l[tid][1] = esh[ge * 4 + 2];
        sh1l[tid][2] = esh[ge * 4 + 3];
    }
    __syncthreads();
    for (int idx = tid; idx < 64 * 80; idx += 128) {
        int e = idx / 80, q = idx - e * 80;
        xng[e][q] = xn[srcl[e] * 80 + q];
    }
    __syncthreads();
    for (int idx = tid; idx < 64 * 16; idx += 128) {
        int e = idx >> 4, i = idx & 15;
        const float* vb = &xng[e][32 + 3 * i];
        innr[e][i] = A2ISQ * (vb[0] * sh1l[e][0] + vb[1] * sh1l[e][1] + vb[2] * sh1l[e][2]);
    }
    __syncthreads();

    // ---------------- per-wave prologue: fragments ----------------
    int el[2] = { wid * 32 + l15, wid * 32 + 16 + l15 };
    float f1[2], f4e[2];
    bf16x8 hfr[2][4], p1f[2], p2f[2], xsf[2], xvf[3][2];
#pragma unroll
    for (int et = 0; et < 2; et++) {
        f1[et] = A1C * sh0l[el[et]];
        f4e[et] = A4C * sh0l[el[et]];
        int ge = e0 + el[et];
        if (ge >= E_EDGES) ge = E_EDGES - 1;
        const __hip_bfloat16* hr = h2b + ge * HID;
#pragma unroll
        for (int kk = 0; kk < 4; kk++)
            hfr[et][kk] = *(const bf16x8*)(hr + kk * 32 + ib);
        const float* xr = &xng[el[et]][0];
        bf16x8 xs8, p18, p28;
#pragma unroll
        for (int j = 0; j < 8; j++) {
            float xv_ = xr[ib + j];
            xs8[j] = bf16r(xv_);
            p18[j] = bf16r(xv_ * f1[et]);
            p28[j] = (ib + j < 16) ? bf16r(innr[el[et]][ib + j]) : (short)0;
        }
        xsf[et] = xs8; p1f[et] = p18; p2f[et] = p28;
#pragma unroll
        for (int m = 0; m < 3; m++) {
            bf16x8 t8;
#pragma unroll
            for (int j = 0; j < 8; j++) {
                int i = ib + j;
                float v = (i < 16) ? xr[32 + 3 * i + m] : 0.f;
                t8[j] = bf16r(v);
            }
            xvf[m][et] = t8;
        }
    }
    bf16x8 ba1[2], ba2[2], ba3, ba4;
    ba1[0] = *(const bf16x8*)(biasf + lane * 8);
    ba1[1] = *(const bf16x8*)(biasf + 512 + lane * 8);
    ba2[0] = *(const bf16x8*)(biasf + 1024 + lane * 8);
    ba2[1] = *(const bf16x8*)(biasf + 1536 + lane * 8);
    ba3    = *(const bf16x8*)(biasf + 2048 + lane * 8);
    ba4    = *(const bf16x8*)(biasf + 2560 + lane * 8);

    const f32x4 zf = {0.f, 0.f, 0.f, 0.f};
    f32x4 msgS[2][2], q3[2], qv[3][2];   // [ohalf][et], [et], [m][et]
#pragma unroll
    for (int et = 0; et < 2; et++) {
#pragma unroll
        for (int oh = 0; oh < 2; oh++) {
            f32x4 a = __builtin_amdgcn_mfma_f32_16x16x32_bf16(ba1[oh], p1f[et], zf, 0, 0, 0);
            msgS[oh][et] = __builtin_amdgcn_mfma_f32_16x16x32_bf16(ba2[oh], p2f[et], a, 0, 0, 0);
        }
        q3[et] = __builtin_amdgcn_mfma_f32_16x16x32_bf16(ba3, xsf[et], zf, 0, 0, 0);
#pragma unroll
        for (int m = 0; m < 3; m++)
            qv[m][et] = __builtin_amdgcn_mfma_f32_16x16x32_bf16(ba4, xvf[m][et], zf, 0, 0, 0);
    }

    // ---------------- main loop: 72 chunks, reg double-buffer, no barriers ------
    const bf16x8* gp = (const bf16x8*)mw3f;   // 8-elem (16B) units; chunk = 512 units

    auto compute_chunk = [&](int n, bf16x8 (&A)[8]) {
        f32x4 acc[2][2];
#pragma unroll
        for (int half = 0; half < 2; half++) {
            f32x4 a0 = zf, a1 = zf;
#pragma unroll
            for (int kk = 0; kk < 4; kk++) {
                a0 = __builtin_amdgcn_mfma_f32_16x16x32_bf16(A[half * 4 + kk], hfr[0][kk], a0, 0, 0, 0);
                a1 = __builtin_amdgcn_mfma_f32_16x16x32_bf16(A[half * 4 + kk], hfr[1][kk], a1, 0, 0, 0);
            }
            acc[half][0] = a0; acc[half][1] = a1;
        }
        if (n < 32) {              // w1: i = n
            float p0 = f1[0] * xng[el[0]][n];
            float p1 = f1[1] * xng[el[1]][n];
#pragma unroll
            for (int half = 0; half < 2; half++)
#pragma unroll
                for (int r = 0; r < 4; r++) {
                    msgS[half][0][r] += p0 * acc[half][0][r];
                    msgS[half][1][r] += p1 * acc[half][1][r];
                }
        } else if (n < 48) {       // w2: i = n-32 (innr pre-scaled)
            float p0 = innr[el[0]][n - 32];
            float p1 = innr[el[1]][n - 32];
#pragma unroll
            for (int half = 0; half < 2; half++)
#pragma unroll
                for (int r = 0; r < 4; r++) {
                    msgS[half][0][r] += p0 * acc[half][0][r];
                    msgS[half][1][r] += p1 * acc[half][1][r];
                }
        } else if (n < 64) {       // w3: i = 2*(n-48)+half (A3 folded at end)
#pragma unroll
            for (int half = 0; half < 2; half++) {
                int i = 2 * (n - 48) + half;
                float p0 = xng[el[0]][i];
                float p1 = xng[el[1]][i];
#pragma unroll
                for (int r = 0; r < 4; r++) {
                    q3[0][r] += p0 * acc[half][0][r];
                    q3[1][r] += p1 * acc[half][1][r];
                }
            }
        } else {                   // w4: i = 2*(n-64)+half (A4*sh0 folded at end)
#pragma unroll
            for (int half = 0; half < 2; half++) {
                int i = 2 * (n - 64) + half;
#pragma unroll
                for (int m = 0; m < 3; m++) {
                    float p0 = xng[el[0]][32 + 3 * i + m];
                    float p1 = xng[el[1]][32 + 3 * i + m];
#pragma unroll
                    for (int r = 0; r < 4; r++) {
                        qv[m][0][r] += p0 * acc[half][0][r];
                        qv[m][1][r] += p1 * acc[half][1][r];
                    }
                }
            }
        }
    };

    bf16x8 A0[8], A1[8];
#pragma unroll
    for (int f = 0; f < 8; f++) A0[f] = gp[f * 64 + lane];
    for (int n = 0; n < 72; n += 2) {
        const bf16x8* g1 = gp + (n + 1) * 512;
#pragma unroll
        for (int f = 0; f < 8; f++) A1[f] = g1[f * 64 + lane];
        compute_chunk(n, A0);
        if (n + 2 < 72) {
            const bf16x8* g2 = gp + (n + 2) * 512;
#pragma unroll
            for (int f = 0; f < 8; f++) A0[f] = g2[f * 64 + lane];
        }
        compute_chunk(n + 1, A1);
    }

    // ---------------- epilogue: weight + scatter-add ----------------
#pragma unroll
    for (int et = 0; et < 2; et++) {
        int le = el[et];
        float ew = ewl[le];
        int d = dstl[le];
        float s0 = sh1l[le][0], s1 = sh1l[le][1], s2 = sh1l[le][2];
        float b4 = f4e[et];
        float* ag = agg + d * 80;
        int ob = q4 * 4;
#pragma unroll
        for (int r = 0; r < 4; r++) {
            int o = ob + r;
            atomicAdd(ag + o, msgS[0][et][r] * ew);
            atomicAdd(ag + 16 + o, msgS[1][et][r] * ew);
            float qq = A3C * q3[et][r];
            atomicAdd(ag + 32 + o * 3 + 0, (qq * s0 + b4 * qv[0][et][r]) * ew);
            atomicAdd(ag + 32 + o * 3 + 1, (qq * s1 + b4 * qv[1][et][r]) * ew);
            atomicAdd(ag + 32 + o * 3 + 2, (qq * s2 + b4 * qv[2][et][r]) * ew);
        }
    }
}

// ---------------- K4: per-node update (one 64-thread block per node) ------------
__global__ void k_update(
    const float* __restrict__ x, const float* __restrict__ xn,
    const float* __restrict__ agg, const float* __restrict__ den,
    const float* __restrict__ Ws, const float* __restrict__ Wv,
    const float* __restrict__ Us, const float* __restrict__ Uv,
    const float* __restrict__ Ss, const float* __restrict__ Sv,
    const float* __restrict__ rsp, float* __restrict__ out) {
    int n = blockIdx.x, t = threadIdx.x;
    __shared__ float ag[DD];
    __shared__ float xnl[DD];
    __shared__ float sg[NS];
    __shared__ float gt[NV];
    __shared__ float vg[48];
    float idv = 1.0f / fmaxf(den[n], 1e-8f);
    ag[t] = agg[n * DD + t] * idv;
    if (t < 16) ag[64 + t] = agg[n * DD + 64 + t] * idv;
    xnl[t] = xn[n * DD + t];
    if (t < 16) xnl[64 + t] = xn[n * DD + 64 + t];
    __syncthreads();
    const float iqs = 0.17677669529663687f;
    const float iqv = 0.25f;
    if (t < 48) {
        float acc = 0.f;
#pragma unroll
        for (int i = 0; i < NS; i++) acc += ag[i] * Ws[i * 48 + t];
        acc *= iqs;
        if (t < NS) sg[t] = silu_f(acc);
        else gt[t - NS] = sigm(acc);
    }
    __syncthreads();
    if (t < 48) {
        int o = t / 3, m = t - 3 * o;
        float acc = 0.f;
#pragma unroll
        for (int i = 0; i < NV; i++) acc += ag[NS + 3 * i + m] * Wv[i * NV + o];
        vg[t] = acc * iqv * gt[o];
    }
    __syncthreads();
    float rs = rsp[0];
    if (t < NS) {
        float us = 0.f, ss = 0.f;
#pragma unroll
        for (int i = 0; i < NS; i++) { us += sg[i] * Us[i * NS + t]; ss += xnl[i] * Ss[i * NS + t]; }
        out[n * DD + t] = x[n * DD + t] + rs * ((ss + us) * iqs);
    }
    if (t < 48) {
        int o = t / 3, m = t - 3 * o;
        float uv = 0.f, sv = 0.f;
#pragma unroll
        for (int i = 0; i < NV; i++) { uv += vg[3 * i + m] * Uv[i * NV + o]; sv += xnl[NS + 3 * i + m] * Sv[i * NV + o]; }
        out[n * DD + NS + t] = x[n * DD + NS + t] + rs * ((sv + uv) * iqv);
    }
}

extern "C" void kernel_launch(void* const* d_in, const int* in_sizes, int n_in,
                              void* d_out, int out_size, void* d_ws, size_t ws_size,
                              hipStream_t stream) {
    (void)in_sizes; (void)n_in; (void)out_size; (void)ws_size;
    const float* x    = (const float*)d_in[0];
    const int*   esrc = (const int*)d_in[1];
    const int*   edst = (const int*)d_in[2];
    const float* esh  = (const float*)d_in[3];
    const float* erbf = (const float*)d_in[4];
    const float* elen = (const float*)d_in[5];
    const float* nw   = (const float*)d_in[6];
    const float* nb   = (const float*)d_in[7];
    const float* mw1  = (const float*)d_in[8];
    const float* mb1  = (const float*)d_in[9];
    const float* mw2  = (const float*)d_in[10];
    const float* mb2  = (const float*)d_in[11];
    const float* mw3  = (const float*)d_in[12];
    const float* mb3  = (const float*)d_in[13];
    const float* gw1  = (const float*)d_in[14];
    const float* gb1  = (const float*)d_in[15];
    const float* gw2  = (const float*)d_in[16];
    const float* gb2  = (const float*)d_in[17];
    const float* Ws   = (const float*)d_in[18];
    const float* Wv   = (const float*)d_in[19];
    const float* Us   = (const float*)d_in[20];
    const float* Uv   = (const float*)d_in[21];
    const float* Ss   = (const float*)d_in[22];
    const float* Sv   = (const float*)d_in[23];
    const float* rsp  = (const float*)d_in[24];
    float* out = (float*)d_out;
    float* ws  = (float*)d_ws;

    float* xn  = ws;                          // [0, 256000)
    float* agg = ws + 256000;                 // [256000, 512000)
    float* den = ws + 512000;                 // [512000, 515200)
    float* ewg = ws + 515200;                 // [515200, 565200)
    __hip_bfloat16* h1b  = (__hip_bfloat16*)(ws + 565200);    // 6.4M bf16
    __hip_bfloat16* h2b  = (__hip_bfloat16*)(ws + 3765200);   // 6.4M bf16
    __hip_bfloat16* mw3f = (__hip_bfloat16*)(ws + 6965200);   // 294912 bf16
    __hip_bfloat16* bias = (__hip_bfloat16*)(ws + 7112656);   // 3072 bf16
    __hip_bfloat16* mw2f = (__hip_bfloat16*)(ws + 7114192);   // 16384 bf16

    hipMemsetAsync(agg, 0, (256000 + 3200) * sizeof(float), stream);
    k_prep<<<153, 256, 0, stream>>>(mw3, mw2, mb3, mw3f, mw2f, bias);
    k_norm<<<N_NODES, 64, 0, stream>>>(x, nw, nb, xn);
    k_edge_mlp1<<<782, 256, 0, stream>>>(erbf, elen, edst, mw1, mb1, gw1, gb1, gw2, gb2, h1b, ewg, den);
    k_mlp2<<<391, 256, 0, stream>>>(h1b, mw2f, mb2, h2b);
    k_msg<<<782, 128, 0, stream>>>(xn, h2b, ewg, esrc, edst, esh, mw3f, bias, agg);
    k_update<<<N_NODES, 64, 0, stream>>>(x, xn, agg, den, Ws, Wv, Us, Uv, Ss, Sv, rsp, out);
}

// Round 4
// 312.624 us; speedup vs baseline: 1.9198x; 1.1870x over previous
//
#include <hip/hip_runtime.h>
#include <hip/hip_bf16.h>
#include <math.h>

#define N_NODES 3200
#define E_EDGES 50000
#define RBFN 16
#define HID 128
#define NS 32
#define NV 16
#define DD 80
#define WNUM 2304
#define CUTF 5.0f
#define EPSF 1e-8f

#define A1C 0.125f                  // 1/sqrt(2*NS)
#define A2C 0.17677669529663687f    // 1/sqrt(2*NV)
#define A3C 0.125f
#define A4C 0.17677669529663687f
#define ISQ3 0.5773502691896258f
#define A2ISQ 0.10206207261596575f  // A2C * ISQ3

typedef __attribute__((ext_vector_type(4))) float f32x4;
typedef __attribute__((ext_vector_type(8))) short bf16x8;

__device__ __forceinline__ float sigm(float x) { return 1.0f / (1.0f + __expf(-x)); }
__device__ __forceinline__ float silu_f(float x) { return x * sigm(x); }

__device__ __forceinline__ short bf16r(float x) {
    union { float f; unsigned u; } v; v.f = x;
    unsigned r = (v.u + 0x7fffu + ((v.u >> 16) & 1u)) >> 16;
    return (short)r;
}

// ---------------- CSR sort: histogram / scan / scatter --------------------------
__global__ void k_hist(const int* __restrict__ edst, int* __restrict__ hist) {
    int e = blockIdx.x * 256 + threadIdx.x;
    if (e < E_EDGES) atomicAdd(&hist[edst[e]], 1);
}

// single WG, 256 threads, 13 elems/thread (3328 >= 3200). start has 3201 entries.
__global__ __launch_bounds__(256) void k_scan(const int* __restrict__ hist, int* __restrict__ start) {
    __shared__ int part[256];
    int t = threadIdx.x;
    int loc[13];
    int s = 0;
#pragma unroll
    for (int j = 0; j < 13; j++) {
        int idx = t * 13 + j;
        int v = (idx < N_NODES) ? hist[idx] : 0;
        loc[j] = s; s += v;
    }
    part[t] = s;
    __syncthreads();
    for (int off = 1; off < 256; off <<= 1) {
        int v = part[t];
        int add = (t >= off) ? part[t - off] : 0;
        __syncthreads();
        part[t] = v + add;
        __syncthreads();
    }
    int pre = (t == 0) ? 0 : part[t - 1];
#pragma unroll
    for (int j = 0; j < 13; j++) {
        int idx = t * 13 + j;
        if (idx < N_NODES) start[idx] = pre + loc[j];
    }
    if (t == 255) start[N_NODES] = part[255];
}

__global__ void k_scatter(const int* __restrict__ edst, const int* __restrict__ start,
                          int* __restrict__ cur, int* __restrict__ perm) {
    int e = blockIdx.x * 256 + threadIdx.x;
    if (e < E_EDGES) {
        int d = edst[e];
        int pos = start[d] + atomicAdd(&cur[d], 1);
        perm[pos] = e;
    }
}

// ---------------- K0: prep — frag-linear bf16 images of mw3 / mw2 + bias frags --
__global__ void k_prep(const float* __restrict__ mw3, const float* __restrict__ mw2,
                       const float* __restrict__ mb3,
                       __hip_bfloat16* __restrict__ mw3f, __hip_bfloat16* __restrict__ mw2f,
                       __hip_bfloat16* __restrict__ biasf) {
    __shared__ __hip_bfloat16 st[2048];
    int b = blockIdx.x, tid = threadIdx.x;
    if (b < 152) {
        bool is3 = b < 144;
        int t = is3 ? b : (b - 144);
        for (int idx = tid; idx < 2048; idx += 256) {
            int k = idx >> 4, c = idx & 15;
            float v = is3 ? mw3[k * WNUM + t * 16 + c] : mw2[k * HID + t * 16 + c];
            int kk = k >> 5, q4 = (k >> 3) & 3, j = k & 7;
            st[kk * 512 + (q4 * 16 + c) * 8 + j] = __float2bfloat16(v);
        }
        __syncthreads();
        __hip_bfloat16* dst = is3 ? (mw3f + t * 2048) : (mw2f + t * 2048);
        ((bf16x8*)dst)[tid] = ((const bf16x8*)st)[tid];
    } else {
        for (int idx = tid; idx < 3072; idx += 256) {
            float val;
            if (idx < 1024) {
                int oh = idx >> 9, l = (idx >> 3) & 63, j = idx & 7;
                int o = oh * 16 + (l & 15), i = (l >> 4) * 8 + j;
                val = mb3[i * 32 + o];
            } else if (idx < 2048) {
                int t = idx - 1024;
                int oh = t >> 9, l = (t >> 3) & 63, j = t & 7;
                int o = oh * 16 + (l & 15), i = (l >> 4) * 8 + j;
                val = (i < 16) ? mb3[1024 + i * 32 + o] : 0.f;
            } else if (idx < 2560) {
                int t = idx - 2048;
                int l = t >> 3, j = t & 7;
                int o = l & 15, i = (l >> 4) * 8 + j;
                val = mb3[1536 + i * 16 + o];
            } else {
                int t = idx - 2560;
                int l = t >> 3, j = t & 7;
                int o = l & 15, i = (l >> 4) * 8 + j;
                val = (i < 16) ? mb3[2048 + i * 16 + o] : 0.f;
            }
            biasf[idx] = __float2bfloat16(val);
        }
    }
}

// ---------------- K1: irrep norm  (one 64-thread block per node) ----------------
__global__ void k_norm(const float* __restrict__ x, const float* __restrict__ nw,
                       const float* __restrict__ nb, float* __restrict__ xn) {
    int n = blockIdx.x, t = threadIdx.x;
    __shared__ float row[DD];
    const float* xr = x + n * DD;
    row[t] = xr[t];
    if (t < DD - 64) row[64 + t] = xr[64 + t];
    __syncthreads();
    float mean = 0.f;
#pragma unroll
    for (int i = 0; i < NS; i++) mean += row[i];
    mean *= (1.0f / NS);
    float var = 0.f;
#pragma unroll
    for (int i = 0; i < NS; i++) { float d = row[i] - mean; var += d * d; }
    var *= (1.0f / NS);
    float inv = rsqrtf(var + EPSF);
    if (t < NS) {
        float v = (row[t] - mean) * inv;
        xn[n * DD + t] = v * nw[t] + nb[t];
    }
    if (t < 48) {
        int j = t / 3;
        float v0 = row[NS + 3 * j], v1 = row[NS + 3 * j + 1], v2 = row[NS + 3 * j + 2];
        float rms = sqrtf((v0 * v0 + v1 * v1 + v2 * v2) * (1.0f / 3.0f) + EPSF);
        float v = row[NS + t] / rms;
        xn[n * DD + NS + t] = v * nw[NS + t] + nb[NS + t];
    }
}

// ------------- K2a: edge MLP layer 1 + gate + cutoff (no atomics) ---------------
__global__ __launch_bounds__(256) void k_edge_mlp1(
    const float* __restrict__ rbf, const float* __restrict__ elen,
    const float* __restrict__ mw1, const float* __restrict__ mb1,
    const float* __restrict__ gw1, const float* __restrict__ gb1,
    const float* __restrict__ gw2, const float* __restrict__ gb2,
    __hip_bfloat16* __restrict__ h1b, float* __restrict__ ewg) {
    int wv = __builtin_amdgcn_readfirstlane(threadIdx.x >> 6) + blockIdx.x * 4;
    int lane = threadIdx.x & 63;
    int eb = wv * 16;
    if (eb >= E_EDGES) return;
    int c0 = lane, c1 = 64 + lane;
    float t0[16], t1[16], g0[16], g1[16];
    float b0 = mb1[c0], b1 = mb1[c1], gb0v = gb1[c0], gb1v = gb1[c1];
#pragma unroll
    for (int e = 0; e < 16; e++) { t0[e] = b0; t1[e] = b1; g0[e] = gb0v; g1[e] = gb1v; }
#pragma unroll
    for (int r = 0; r < RBFN; r++) {
        float w0 = mw1[r * HID + c0], w1 = mw1[r * HID + c1];
        float v0 = gw1[r * HID + c0], v1 = gw1[r * HID + c1];
#pragma unroll
        for (int e = 0; e < 16; e++) {
            float rv = rbf[(eb + e) * RBFN + r];
            t0[e] += rv * w0; t1[e] += rv * w1;
            g0[e] += rv * v0; g1[e] += rv * v1;
        }
    }
    float q0 = gw2[c0], q1 = gw2[c1];
    float gb2v = gb2[0];
#pragma unroll
    for (int e = 0; e < 16; e++) {
        h1b[(eb + e) * HID + c0] = __float2bfloat16(silu_f(t0[e]));
        h1b[(eb + e) * HID + c1] = __float2bfloat16(silu_f(t1[e]));
        float p = silu_f(g0[e]) * q0 + silu_f(g1[e]) * q1;
        p += __shfl_xor(p, 1);  p += __shfl_xor(p, 2);  p += __shfl_xor(p, 4);
        p += __shfl_xor(p, 8);  p += __shfl_xor(p, 16); p += __shfl_xor(p, 32);
        if (lane == 0) {
            float len = elen[eb + e];
            float cut = (len <= CUTF) ? 0.5f * (cosf(3.14159265358979f * len / CUTF) + 1.0f) : 0.f;
            ewg[eb + e] = cut * sigm(p + gb2v);
        }
    }
}

// ---------------- K2b: edge MLP layer 2 as bf16 MFMA (128x128 GEMM) -------------
__global__ __launch_bounds__(256) void k_mlp2(
    const __hip_bfloat16* __restrict__ h1b, const __hip_bfloat16* __restrict__ mw2f,
    const float* __restrict__ mb2, __hip_bfloat16* __restrict__ h2b) {
    int tid = threadIdx.x;
    int wid = __builtin_amdgcn_readfirstlane(tid >> 6);
    int lane = tid & 63, q4 = lane >> 4, l15 = lane & 15;
    int base = blockIdx.x * 128 + wid * 32;
    bf16x8 af[2][4];
#pragma unroll
    for (int et = 0; et < 2; et++) {
        int ge = base + et * 16 + l15;
        if (ge >= E_EDGES) ge = E_EDGES - 1;
#pragma unroll
        for (int kk = 0; kk < 4; kk++)
            af[et][kk] = *(const bf16x8*)(h1b + ge * HID + kk * 32 + q4 * 8);
    }
    const f32x4 zf = {0.f, 0.f, 0.f, 0.f};
    f32x4 acc[8][2];
#pragma unroll
    for (int ct = 0; ct < 8; ct++) { acc[ct][0] = zf; acc[ct][1] = zf; }
#pragma unroll
    for (int ct = 0; ct < 8; ct++) {
#pragma unroll
        for (int kk = 0; kk < 4; kk++) {
            bf16x8 bw = *(const bf16x8*)(mw2f + (ct * 4 + kk) * 512 + lane * 8);
            acc[ct][0] = __builtin_amdgcn_mfma_f32_16x16x32_bf16(af[0][kk], bw, acc[ct][0], 0, 0, 0);
            acc[ct][1] = __builtin_amdgcn_mfma_f32_16x16x32_bf16(af[1][kk], bw, acc[ct][1], 0, 0, 0);
        }
    }
#pragma unroll
    for (int ct = 0; ct < 8; ct++) {
        float bias = mb2[ct * 16 + l15];
#pragma unroll
        for (int et = 0; et < 2; et++) {
#pragma unroll
            for (int r = 0; r < 4; r++) {
                int ge = base + et * 16 + q4 * 4 + r;
                if (ge < E_EDGES)
                    h2b[ge * HID + ct * 16 + l15] = __float2bfloat16(silu_f(acc[ct][et][r] + bias));
            }
        }
    }
}

// -------- K3: fused bf16-MFMA tpw GEMM + tensor-product messages ----------------
// Edges processed in dst-sorted (perm) order; per-edge weighted message STORED to
// msgbuf[slot*80+ch] — no atomics. 72 chunks, reg double-buffer, no main barriers.
__global__ __launch_bounds__(128) void k_msg(
    const float* __restrict__ xn, const __hip_bfloat16* __restrict__ h2b,
    const float* __restrict__ ewg, const int* __restrict__ esrc,
    const int* __restrict__ perm, const float* __restrict__ esh,
    const __hip_bfloat16* __restrict__ mw3f, const __hip_bfloat16* __restrict__ biasf,
    float* __restrict__ msgbuf, float* __restrict__ ewp) {
    __shared__ float xng[64][84];
    __shared__ float innr[64][17];
    __shared__ float sh1l[64][4];
    __shared__ float sh0l[64], ewl[64];
    __shared__ int srcl[64], gel[64];

    const int tid = threadIdx.x;
    const int wid = __builtin_amdgcn_readfirstlane(tid >> 6);
    const int lane = tid & 63;
    const int q4 = lane >> 4;
    const int l15 = lane & 15;
    const int ib = q4 * 8;
    const int e0 = blockIdx.x * 64;

    if (tid < 64) {
        int slot = e0 + tid;
        bool v = slot < E_EDGES;
        int ge = v ? perm[slot] : 0;
        gel[tid] = ge;
        srcl[tid] = esrc[ge];
        float ew = v ? ewg[ge] : 0.f;
        ewl[tid] = ew;
        ewp[slot] = ew;
        sh0l[tid] = esh[ge * 4];
        sh1l[tid][0] = esh[ge * 4 + 1];
        sh1l[tid][1] = esh[ge * 4 + 2];
        sh1l[tid][2] = esh[ge * 4 + 3];
    }
    __syncthreads();
    for (int idx = tid; idx < 64 * 80; idx += 128) {
        int e = idx / 80, q = idx - e * 80;
        xng[e][q] = xn[srcl[e] * 80 + q];
    }
    __syncthreads();
    for (int idx = tid; idx < 64 * 16; idx += 128) {
        int e = idx >> 4, i = idx & 15;
        const float* vb = &xng[e][32 + 3 * i];
        innr[e][i] = A2ISQ * (vb[0] * sh1l[e][0] + vb[1] * sh1l[e][1] + vb[2] * sh1l[e][2]);
    }
    __syncthreads();

    // ---------------- per-wave prologue: fragments ----------------
    int el[2] = { wid * 32 + l15, wid * 32 + 16 + l15 };
    float f1[2], f4e[2];
    bf16x8 hfr[2][4], p1f[2], p2f[2], xsf[2], xvf[3][2];
#pragma unroll
    for (int et = 0; et < 2; et++) {
        f1[et] = A1C * sh0l[el[et]];
        f4e[et] = A4C * sh0l[el[et]];
        int ge = gel[el[et]];
        const __hip_bfloat16* hr = h2b + ge * HID;
#pragma unroll
        for (int kk = 0; kk < 4; kk++)
            hfr[et][kk] = *(const bf16x8*)(hr + kk * 32 + ib);
        const float* xr = &xng[el[et]][0];
        bf16x8 xs8, p18, p28;
#pragma unroll
        for (int j = 0; j < 8; j++) {
            float xv_ = xr[ib + j];
            xs8[j] = bf16r(xv_);
            p18[j] = bf16r(xv_ * f1[et]);
            p28[j] = (ib + j < 16) ? bf16r(innr[el[et]][ib + j]) : (short)0;
        }
        xsf[et] = xs8; p1f[et] = p18; p2f[et] = p28;
#pragma unroll
        for (int m = 0; m < 3; m++) {
            bf16x8 t8;
#pragma unroll
            for (int j = 0; j < 8; j++) {
                int i = ib + j;
                float v = (i < 16) ? xr[32 + 3 * i + m] : 0.f;
                t8[j] = bf16r(v);
            }
            xvf[m][et] = t8;
        }
    }
    bf16x8 ba1[2], ba2[2], ba3, ba4;
    ba1[0] = *(const bf16x8*)(biasf + lane * 8);
    ba1[1] = *(const bf16x8*)(biasf + 512 + lane * 8);
    ba2[0] = *(const bf16x8*)(biasf + 1024 + lane * 8);
    ba2[1] = *(const bf16x8*)(biasf + 1536 + lane * 8);
    ba3    = *(const bf16x8*)(biasf + 2048 + lane * 8);
    ba4    = *(const bf16x8*)(biasf + 2560 + lane * 8);

    const f32x4 zf = {0.f, 0.f, 0.f, 0.f};
    f32x4 msgS[2][2], q3[2], qv[3][2];
#pragma unroll
    for (int et = 0; et < 2; et++) {
#pragma unroll
        for (int oh = 0; oh < 2; oh++) {
            f32x4 a = __builtin_amdgcn_mfma_f32_16x16x32_bf16(ba1[oh], p1f[et], zf, 0, 0, 0);
            msgS[oh][et] = __builtin_amdgcn_mfma_f32_16x16x32_bf16(ba2[oh], p2f[et], a, 0, 0, 0);
        }
        q3[et] = __builtin_amdgcn_mfma_f32_16x16x32_bf16(ba3, xsf[et], zf, 0, 0, 0);
#pragma unroll
        for (int m = 0; m < 3; m++)
            qv[m][et] = __builtin_amdgcn_mfma_f32_16x16x32_bf16(ba4, xvf[m][et], zf, 0, 0, 0);
    }

    // ---------------- main loop: 72 chunks, reg double-buffer -------------------
    const bf16x8* gp = (const bf16x8*)mw3f;

    auto compute_chunk = [&](int n, bf16x8 (&A)[8]) {
        f32x4 acc[2][2];
#pragma unroll
        for (int half = 0; half < 2; half++) {
            f32x4 a0 = zf, a1 = zf;
#pragma unroll
            for (int kk = 0; kk < 4; kk++) {
                a0 = __builtin_amdgcn_mfma_f32_16x16x32_bf16(A[half * 4 + kk], hfr[0][kk], a0, 0, 0, 0);
                a1 = __builtin_amdgcn_mfma_f32_16x16x32_bf16(A[half * 4 + kk], hfr[1][kk], a1, 0, 0, 0);
            }
            acc[half][0] = a0; acc[half][1] = a1;
        }
        if (n < 32) {
            float p0 = f1[0] * xng[el[0]][n];
            float p1 = f1[1] * xng[el[1]][n];
#pragma unroll
            for (int half = 0; half < 2; half++)
#pragma unroll
                for (int r = 0; r < 4; r++) {
                    msgS[half][0][r] += p0 * acc[half][0][r];
                    msgS[half][1][r] += p1 * acc[half][1][r];
                }
        } else if (n < 48) {
            float p0 = innr[el[0]][n - 32];
            float p1 = innr[el[1]][n - 32];
#pragma unroll
            for (int half = 0; half < 2; half++)
#pragma unroll
                for (int r = 0; r < 4; r++) {
                    msgS[half][0][r] += p0 * acc[half][0][r];
                    msgS[half][1][r] += p1 * acc[half][1][r];
                }
        } else if (n < 64) {
#pragma unroll
            for (int half = 0; half < 2; half++) {
                int i = 2 * (n - 48) + half;
                float p0 = xng[el[0]][i];
                float p1 = xng[el[1]][i];
#pragma unroll
                for (int r = 0; r < 4; r++) {
                    q3[0][r] += p0 * acc[half][0][r];
                    q3[1][r] += p1 * acc[half][1][r];
                }
            }
        } else {
#pragma unroll
            for (int half = 0; half < 2; half++) {
                int i = 2 * (n - 64) + half;
#pragma unroll
                for (int m = 0; m < 3; m++) {
                    float p0 = xng[el[0]][32 + 3 * i + m];
                    float p1 = xng[el[1]][32 + 3 * i + m];
#pragma unroll
                    for (int r = 0; r < 4; r++) {
                        qv[m][0][r] += p0 * acc[half][0][r];
                        qv[m][1][r] += p1 * acc[half][1][r];
                    }
                }
            }
        }
    };

    bf16x8 A0[8], A1[8];
#pragma unroll
    for (int f = 0; f < 8; f++) A0[f] = gp[f * 64 + lane];
    for (int n = 0; n < 72; n += 2) {
        const bf16x8* g1 = gp + (n + 1) * 512;
#pragma unroll
        for (int f = 0; f < 8; f++) A1[f] = g1[f * 64 + lane];
        compute_chunk(n, A0);
        if (n + 2 < 72) {
            const bf16x8* g2 = gp + (n + 2) * 512;
#pragma unroll
            for (int f = 0; f < 8; f++) A0[f] = g2[f * 64 + lane];
        }
        compute_chunk(n + 1, A1);
    }

    // ---------------- epilogue: weight + plain stores to msgbuf -----------------
#pragma unroll
    for (int et = 0; et < 2; et++) {
        int le = el[et];
        float ew = ewl[le];
        float s0 = sh1l[le][0], s1 = sh1l[le][1], s2 = sh1l[le][2];
        float b4 = f4e[et];
        float* mrow = msgbuf + (size_t)(e0 + le) * 80;
        int ob = q4 * 4;
#pragma unroll
        for (int r = 0; r < 4; r++) {
            int o = ob + r;
            mrow[o] = msgS[0][et][r] * ew;
            mrow[16 + o] = msgS[1][et][r] * ew;
            float qq = A3C * q3[et][r];
            mrow[32 + o * 3 + 0] = (qq * s0 + b4 * qv[0][et][r]) * ew;
            mrow[32 + o * 3 + 1] = (qq * s1 + b4 * qv[1][et][r]) * ew;
            mrow[32 + o * 3 + 2] = (qq * s2 + b4 * qv[2][et][r]) * ew;
        }
    }
}

// ---------------- K3b: segment gather + divide (one WG per node) ----------------
__global__ __launch_bounds__(128) void k_agg(
    const float* __restrict__ msgbuf, const float* __restrict__ ewp,
    const int* __restrict__ start, float* __restrict__ agg) {
    int n = blockIdx.x, t = threadIdx.x;
    int s = start[n], e = start[n + 1];
    float den = 0.f, acc = 0.f;
    for (int r = s; r < e; r++) {
        den += ewp[r];                       // uniform -> scalar load
        if (t < 80) acc += msgbuf[(size_t)r * 80 + t];
    }
    if (t < 80) agg[n * 80 + t] = acc * (1.0f / fmaxf(den, 1e-8f));
}

// ---------------- K4: per-node update (one 64-thread block per node) ------------
__global__ void k_update(
    const float* __restrict__ x, const float* __restrict__ xn,
    const float* __restrict__ agg,
    const float* __restrict__ Ws, const float* __restrict__ Wv,
    const float* __restrict__ Us, const float* __restrict__ Uv,
    const float* __restrict__ Ss, const float* __restrict__ Sv,
    const float* __restrict__ rsp, float* __restrict__ out) {
    int n = blockIdx.x, t = threadIdx.x;
    __shared__ float ag[DD];
    __shared__ float xnl[DD];
    __shared__ float sg[NS];
    __shared__ float gt[NV];
    __shared__ float vg[48];
    ag[t] = agg[n * DD + t];
    if (t < 16) ag[64 + t] = agg[n * DD + 64 + t];
    xnl[t] = xn[n * DD + t];
    if (t < 16) xnl[64 + t] = xn[n * DD + 64 + t];
    __syncthreads();
    const float iqs = 0.17677669529663687f;
    const float iqv = 0.25f;
    if (t < 48) {
        float acc = 0.f;
#pragma unroll
        for (int i = 0; i < NS; i++) acc += ag[i] * Ws[i * 48 + t];
        acc *= iqs;
        if (t < NS) sg[t] = silu_f(acc);
        else gt[t - NS] = sigm(acc);
    }
    __syncthreads();
    if (t < 48) {
        int o = t / 3, m = t - 3 * o;
        float acc = 0.f;
#pragma unroll
        for (int i = 0; i < NV; i++) acc += ag[NS + 3 * i + m] * Wv[i * NV + o];
        vg[t] = acc * iqv * gt[o];
    }
    __syncthreads();
    float rs = rsp[0];
    if (t < NS) {
        float us = 0.f, ss = 0.f;
#pragma unroll
        for (int i = 0; i < NS; i++) { us += sg[i] * Us[i * NS + t]; ss += xnl[i] * Ss[i * NS + t]; }
        out[n * DD + t] = x[n * DD + t] + rs * ((ss + us) * iqs);
    }
    if (t < 48) {
        int o = t / 3, m = t - 3 * o;
        float uv = 0.f, sv = 0.f;
#pragma unroll
        for (int i = 0; i < NV; i++) { uv += vg[3 * i + m] * Uv[i * NV + o]; sv += xnl[NS + 3 * i + m] * Sv[i * NV + o]; }
        out[n * DD + NS + t] = x[n * DD + NS + t] + rs * ((sv + uv) * iqv);
    }
}

extern "C" void kernel_launch(void* const* d_in, const int* in_sizes, int n_in,
                              void* d_out, int out_size, void* d_ws, size_t ws_size,
                              hipStream_t stream) {
    (void)in_sizes; (void)n_in; (void)out_size; (void)ws_size;
    const float* x    = (const float*)d_in[0];
    const int*   esrc = (const int*)d_in[1];
    const int*   edst = (const int*)d_in[2];
    const float* esh  = (const float*)d_in[3];
    const float* erbf = (const float*)d_in[4];
    const float* elen = (const float*)d_in[5];
    const float* nw   = (const float*)d_in[6];
    const float* nb   = (const float*)d_in[7];
    const float* mw1  = (const float*)d_in[8];
    const float* mb1  = (const float*)d_in[9];
    const float* mw2  = (const float*)d_in[10];
    const float* mb2  = (const float*)d_in[11];
    const float* mw3  = (const float*)d_in[12];
    const float* mb3  = (const float*)d_in[13];
    const float* gw1  = (const float*)d_in[14];
    const float* gb1  = (const float*)d_in[15];
    const float* gw2  = (const float*)d_in[16];
    const float* gb2  = (const float*)d_in[17];
    const float* Ws   = (const float*)d_in[18];
    const float* Wv   = (const float*)d_in[19];
    const float* Us   = (const float*)d_in[20];
    const float* Uv   = (const float*)d_in[21];
    const float* Ss   = (const float*)d_in[22];
    const float* Sv   = (const float*)d_in[23];
    const float* rsp  = (const float*)d_in[24];
    float* out = (float*)d_out;
    float* ws  = (float*)d_ws;

    // ws layout (float offsets). h1b aliases msgbuf region (disjoint lifetimes:
    // h1b dead after k_mlp2; msgbuf born in k_msg).
    float* xn     = ws;                       // 256000
    float* agg    = ws + 256000;              // 256000
    float* ewg    = ws + 512000;              // 50000
    float* ewp    = ws + 562000;              // 50048
    float* msgbuf = ws + 612048;              // 4,003,840  -> ends 4,615,888
    __hip_bfloat16* h1b = (__hip_bfloat16*)(ws + 612048);   // 6.4M bf16 (alias)
    __hip_bfloat16* h2b = (__hip_bfloat16*)(ws + 4615888);  // 6.4M bf16 -> 7,815,888
    int* hist   = (int*)(ws + 7815888);       // 3200
    int* cur    = hist + 3200;                // 3200
    int* startp = cur + 3200;                 // 3201
    int* perm   = startp + 3201;              // 50048 (int region ends @ +59649; pad 59652)
    __hip_bfloat16* mw3f = (__hip_bfloat16*)(ws + 7875540); // 294912 bf16 -> 8,022,996
    __hip_bfloat16* bias = (__hip_bfloat16*)(ws + 8022996); // 3072 bf16  -> 8,024,532
    __hip_bfloat16* mw2f = (__hip_bfloat16*)(ws + 8024532); // 16384 bf16 -> 8,032,724

    hipMemsetAsync(hist, 0, 6400 * sizeof(int), stream);    // hist + cur
    k_hist<<<196, 256, 0, stream>>>(edst, hist);
    k_scan<<<1, 256, 0, stream>>>(hist, startp);
    k_scatter<<<196, 256, 0, stream>>>(edst, startp, cur, perm);
    k_prep<<<153, 256, 0, stream>>>(mw3, mw2, mb3, mw3f, mw2f, bias);
    k_norm<<<N_NODES, 64, 0, stream>>>(x, nw, nb, xn);
    k_edge_mlp1<<<782, 256, 0, stream>>>(erbf, elen, mw1, mb1, gw1, gb1, gw2, gb2, h1b, ewg);
    k_mlp2<<<391, 256, 0, stream>>>(h1b, mw2f, mb2, h2b);
    k_msg<<<782, 128, 0, stream>>>(xn, h2b, ewg, esrc, perm, esh, mw3f, bias, msgbuf, ewp);
    k_agg<<<N_NODES, 128, 0, stream>>>(msgbuf, ewp, startp, agg);
    k_update<<<N_NODES, 64, 0, stream>>>(x, xn, agg, Ws, Wv, Us, Uv, Ss, Sv, rsp, out);
}